// Round 3
// baseline (81.851 us; speedup 1.0000x reference)
//
#include <hip/hip_runtime.h>

// LearnableDemosaick: B=16,H=512,W=512,K=8,f=5, fp32.
// out = is_green ? mosaick : softmax_k(sel_conv) . green_conv
// is_green = (y%2)==(x%2). Edge-clamped 5x5 cross-correlation.
//
// Round-13: 64x32 tile (2x work per block). R12 (-2.8us) showed demosaick is
// per-block fixed-cost/latency bound (cold staging loads - the 268MB ws
// poison sweeps L3 every iteration - plus barrier + A-frag read), not
// throughput bound. Halve block count 4096->2048: each wave now computes 4
// row-pairs (pp=0..3) from a 6-fragment reuse chain F[pp..pp+2] (6 ds_read
// per pp vs 8), halo traffic/output drops 1.25x->1.125x, barriers and
// A-frag reads amortize 2x. Staging: 36 rows x 9 chunks = 324 tasks over
// waves 0-2; wave 3 builds the shared A fragments (R12 structure).
// Numerics identical (passing, absmax 2e-3).

typedef float f32x16 __attribute__((ext_vector_type(16)));
typedef short s16x8  __attribute__((ext_vector_type(8)));

#define HH 512
#define WW 512
#define TW 64
#define TH 32
#define RS 80     // LDS row stride (bf16 elems) = 160 B
#define NROW 36   // TH + 4
#define NCH 9     // chunks of 8 elems per row
#define NTASK (NROW * NCH)   // 324

__device__ __forceinline__ unsigned short bf16rne(float x) {
    unsigned u = __float_as_uint(x);
    u += 0x7fffu + ((u >> 16) & 1u);
    return (unsigned short)(u >> 16);
}
__device__ __forceinline__ int pk2(float hi, float lo) {
    return (int)((((unsigned)bf16rne(hi)) << 16) | (unsigned)bf16rne(lo));
}
__device__ __forceinline__ float hi16(int v) { return __uint_as_float(((unsigned)v) & 0xffff0000u); }
__device__ __forceinline__ float lo16(int v) { return __uint_as_float(((unsigned)v) << 16); }

__global__ __launch_bounds__(256) void demosaick_kernel(
    const float* __restrict__ mos,   // [B,1,H,W]
    const float* __restrict__ sf,    // [5,5,8]
    const float* __restrict__ gf,    // [5,5,8]
    float* __restrict__ out)         // [B,1,H,W]
{
    __shared__ alignas(16) unsigned short tileS[NROW * RS];   // 5760 B
    __shared__ alignas(16) short fragS[64 * 24];              // 3072 B

    const int tid   = threadIdx.x;
    const int tileX = blockIdx.x * TW;    // even
    const int tileY = blockIdx.y * TH;    // even
    const float* img = mos + (size_t)blockIdx.z * HH * WW;

    const int lane = tid & 63;
    const int h    = lane >> 5;

    s16x8 A0 = {0, 0, 0, 0, 0, 0, 0, 0}, A1 = A0, A2 = A0;

    if (tid < 192) {
        // ---- waves 0-2: stage bf16 tile rows tileY-2..tileY+33 (y-clamped),
        //      cols tileX-2..+69; 36 rows x 9 chunks of 8 elems ----
        for (int t = tid; t < NTASK; t += 192) {
            int r = t / NCH, s = t - NCH * r;
            int gy = min(max(tileY - 2 + r, 0), HH - 1);
            const float* rowp = img + (size_t)gy * WW;
            int cx = tileX - 2 + 8 * s;
            int4 d;
            if (cx >= 0 && cx + 8 <= WW) {     // all chunks except x-edge ones
                const float2* src = (const float2*)(rowp + cx);
                float2 v0 = src[0], v1 = src[1], v2 = src[2], v3 = src[3];
                d.x = pk2(v0.y, v0.x);
                d.y = pk2(v1.y, v1.x);
                d.z = pk2(v2.y, v2.x);
                d.w = pk2(v3.y, v3.x);
            } else {                           // bx==0 s==0 / bx==7 s==8 only
                float v[8];
#pragma unroll
                for (int j = 0; j < 8; ++j)
                    v[j] = rowp[min(max(cx + j, 0), WW - 1)];
                d.x = pk2(v[1], v[0]);
                d.y = pk2(v[3], v[2]);
                d.z = pk2(v[5], v[4]);
                d.w = pk2(v[7], v[6]);
            }
            *(int4*)&tileS[r * RS + 8 * s] = d;
        }
    } else {
        // ---- wave 3: build the 64 per-lane A-fragment triples ----
        // A layout (32x32x16): lane holds A[m=lane&31][k=8h+j].
        // M rows 0..15: even-output-row filters (c, type), dx = j-1.
        // M rows 16..31: odd-output-row filters, dx = j. B shared between rows.
        const int m  = lane & 31;
        const int mc = m & 15;
        const int c  = mc >> 1;
        const float* fb = (mc & 1) ? gf : sf;
#pragma unroll
        for (int j = 0; j < 8; ++j) {
            if (m < 16) {                  // even row: taps at rows yE-2..yE+2
                int dx = j - 1;
                if (dx >= 0 && dx < 5) {
                    A0[j] = (short)bf16rne(fb[(h * 5 + dx) * 8 + c]);        // yE-2 / yE-1
                    A1[j] = (short)bf16rne(fb[((2 + h) * 5 + dx) * 8 + c]);  // yE   / yE+1
                    if (h == 0)
                        A2[j] = (short)bf16rne(fb[(20 + dx) * 8 + c]);       // yE+2
                }
            } else {                       // odd row: taps at rows yE-1..yE+3
                if (j < 5) {
                    if (h == 1)
                        A0[j] = (short)bf16rne(fb[j * 8 + c]);               // yE-1
                    A1[j] = (short)bf16rne(fb[((1 + h) * 5 + j) * 8 + c]);   // yE   / yE+1
                    A2[j] = (short)bf16rne(fb[((3 + h) * 5 + j) * 8 + c]);   // yE+2 / yE+3
                }
            }
        }
        s16x8* dst = (s16x8*)&fragS[lane * 24];
        dst[0] = A0; dst[1] = A1; dst[2] = A2;
    }

    __syncthreads();

    if (tid < 192) {                       // waves 0-2 fetch their fragments
        const s16x8* sfr = (const s16x8*)&fragS[lane * 24];
        A0 = sfr[0]; A1 = sfr[1]; A2 = sfr[2];
    }

    const int w = tid >> 6;            // wave -> local rows 8w..8w+7
    const int n = lane & 31;           // pixel column index
    const int* tb = (const int*)tileS; // 40 ints per row
    float* outp = out + (size_t)blockIdx.z * HH * WW;

    // ---- B fragments: unique tile rows 8w+h+{0,2,4,6,8,10} ----
    union { int4 v; s16x8 s; } F[6];
    {
        const int base = (8 * w + h) * 40 + n;
#pragma unroll
        for (int k = 0; k < 6; ++k) {
            const int ia = base + 80 * k;
            F[k].v.x = tb[ia];     F[k].v.y = tb[ia + 1];
            F[k].v.z = tb[ia + 2]; F[k].v.w = tb[ia + 3];
        }
    }

#pragma unroll
    for (int pp = 0; pp < 4; ++pp) {
        const s16x8 Ba = F[pp].s;
        const s16x8 Bb = F[pp + 1].s;
        const s16x8 Bc = F[pp + 2].s;

        f32x16 acc = (f32x16)(0.f);
        acc = __builtin_amdgcn_mfma_f32_32x32x16_bf16(A0, Ba, acc, 0, 0, 0);
        acc = __builtin_amdgcn_mfma_f32_32x32x16_bf16(A1, Bb, acc, 0, 0, 0);
        acc = __builtin_amdgcn_mfma_f32_32x32x16_bf16(A2, Bc, acc, 0, 0, 0);

        // regs 0..7  -> M rows {0..3,8..11}+4h   = even-row (filter,type) pairs
        // regs 8..15 -> M rows {16..19,24..27}+4h = odd-row (filter,type) pairs
        float denE = 0.f, numE = 0.f, denO = 0.f, numO = 0.f;
#pragma unroll
        for (int j = 0; j < 4; ++j) {
            float e  = __expf(acc[2 * j]);
            denE += e;  numE = fmaf(e,  acc[2 * j + 1], numE);
            float eo = __expf(acc[8 + 2 * j]);
            denO += eo; numO = fmaf(eo, acc[9 + 2 * j], numO);
        }
        int ndE  = pk2(numE, denE), ndO = pk2(numO, denO);
        int ndE2 = __shfl_xor(ndE, 32);
        int ndO2 = __shfl_xor(ndO, 32);
        numE += hi16(ndE2); denE += lo16(ndE2);
        numO += hi16(ndO2); denO += lo16(ndO2);
        const float interpE = numE * __builtin_amdgcn_rcpf(denE);
        const float interpO = numO * __builtin_amdgcn_rcpf(denO);

        if (h == 0) {
            const int x0 = tileX + 2 * n;              // even
            const int yE = tileY + 8 * w + 2 * pp;     // even
            // even row: green at x0, interp at x0+1
            float2 stE; stE.x = img[(size_t)yE * WW + x0]; stE.y = interpE;
            *(float2*)(outp + (size_t)yE * WW + x0) = stE;
            // odd row: interp at x0, green at x0+1
            float2 stO; stO.x = interpO; stO.y = img[(size_t)(yE + 1) * WW + x0 + 1];
            *(float2*)(outp + (size_t)(yE + 1) * WW + x0) = stO;
        }
    }
}

extern "C" void kernel_launch(void* const* d_in, const int* in_sizes, int n_in,
                              void* d_out, int out_size, void* d_ws, size_t ws_size,
                              hipStream_t stream) {
    const float* mos = (const float*)d_in[0];
    const float* sf  = (const float*)d_in[1];
    const float* gf  = (const float*)d_in[2];
    float* out = (float*)d_out;

    const int B = in_sizes[0] / (HH * WW);     // 16
    dim3 grid(WW / TW, HH / TH, B);            // (8, 16, 16) = 2048 blocks
    dim3 block(256);
    demosaick_kernel<<<grid, block, 0, stream>>>(mos, sf, gf, out);
    (void)d_ws; (void)ws_size; (void)n_in; (void)out_size;
}